// Round 6
// baseline (214.567 us; speedup 1.0000x reference)
//
#include <hip/hip_runtime.h>

typedef float  f4v  __attribute__((ext_vector_type(4)));
typedef short  s8v  __attribute__((ext_vector_type(8)));

// fp32 -> bf16 round-to-nearest-even
__device__ __forceinline__ ushort f2b(float f) {
    union { float f; unsigned int u; } v; v.f = f;
    unsigned int u = v.u;
    u += 0x7fffu + ((u >> 16) & 1u);
    return (ushort)(u >> 16);
}
__device__ __forceinline__ float b2f(ushort u) {
    union { unsigned int u; float f; } v; v.u = ((unsigned int)u) << 16;
    return v.f;
}

// async global->LDS, 16B per lane. ldsp MUST be wave-uniform; HW writes
// lane i's 16B at ldsp + i*16 (no per-lane scatter, no padding allowed).
__device__ __forceinline__ void async16(const ushort* g, ushort* ldsp) {
    __builtin_amdgcn_global_load_lds(
        (const __attribute__((address_space(1))) unsigned int*)g,
        (__attribute__((address_space(3))) unsigned int*)ldsp, 16, 0, 0);
}

// -------- fused prep: cast x->bf16, zero l, transpose W x3 (one launch) --------
// Blocks 0..8191: cast (256 lanes x float4). Blocks 8192..11263: W transpose
// (reconstructed 32x32x3 tile grid with (32,8) thread mapping).
__global__ __launch_bounds__(256) void prep(const float* __restrict__ in,
                                            ushort* __restrict__ out,
                                            float* __restrict__ l,
                                            const float* __restrict__ w0,
                                            const float* __restrict__ w1,
                                            const float* __restrict__ w2,
                                            ushort* __restrict__ wt) {
    const int L = blockIdx.x, tid = threadIdx.x;
    if (L < 8192) {
        int i = L * 256 + tid;
        if (i < 8192) l[i] = 0.f;   // 4 batches x 2048 rows
        float4 f = ((const float4*)in)[i];
        ushort4 o;
        o.x = f2b(f.x); o.y = f2b(f.y); o.z = f2b(f.z); o.w = f2b(f.w);
        ((ushort4*)out)[i] = o;
        return;
    }
    __shared__ float tile[32][33];
    const int T = L - 8192;
    const int z = T >> 10, rem = T & 1023;
    const int bx = rem & 31, by = rem >> 5;
    const float* W = (z == 0) ? w0 : (z == 1 ? w1 : w2);
    ushort* O = wt + (size_t)z * (1024u * 1024u);
    int x0 = bx * 32, y0 = by * 32;
    int tx = tid & 31, ty = tid >> 5;
    for (int i = 0; i < 4; i++)
        tile[ty + i * 8][tx] = W[(size_t)(y0 + ty + i * 8) * 1024 + x0 + tx];
    __syncthreads();
    for (int i = 0; i < 4; i++)
        O[(size_t)(x0 + ty + i * 8) * 1024 + y0 + tx] = f2b(tile[tx][ty + i * 8]);
}

// ===================== shared pipeline macros (counted-vmcnt) =====================
// Both-sides XOR swizzle: global source col pre-swizzled (lc8 = (lane&7)^lr, row%8==lr),
// ds_read col swizzled by ^(l16&7). Linear LDS dest for global_load_lds.

#define RD_A4(buf_)                                                                   \
    _Pragma("unroll") for (int mi = 0; mi < 4; mi++)                                  \
    _Pragma("unroll") for (int s = 0; s < 2; s++)                                     \
        af[mi][s] = *(const s8v*)&(buf_)[(wm + mi * 16 + l16) * 64 +                  \
                                         (((s * 4 + quad) ^ (l16 & 7)) * 8)];

#define RD_B2(buf_, NI0_)                                                             \
    _Pragma("unroll") for (int j = 0; j < 2; j++)                                     \
    _Pragma("unroll") for (int s = 0; s < 2; s++)                                     \
        bf[j][s] = *(const s8v*)&(buf_)[(wn + ((NI0_) + j) * 16 + l16) * 64 +         \
                                        (((s * 4 + quad) ^ (l16 & 7)) * 8)];

#define MFMA16(NI0_)                                                                  \
    _Pragma("unroll") for (int mi = 0; mi < 4; mi++)                                  \
    _Pragma("unroll") for (int j = 0; j < 2; j++)                                     \
    _Pragma("unroll") for (int s = 0; s < 2; s++)                                     \
        acc[mi][(NI0_) + j] = __builtin_amdgcn_mfma_f32_16x16x32_bf16(                \
            af[mi][s], bf[j][s], acc[mi][(NI0_) + j], 0, 0, 0);

// ---------------- fused QKV projection: 256x192 tile, counted-vmcnt pipeline --------
// Grid 32m x 16n = 512 blocks = exactly 2 full CU-rounds. 8 waves 4m x 2n ->
// wave tile 64x96 (acc[4][6]). LDS 144 KiB: A 3-deep [256][64], B 2-deep [192][64].
// 3 phases x 16 MFMA per K-tile; boundary vmcnt(4) leaves A(t+2) in flight.
__global__ __launch_bounds__(512, 2) void gemm_qkv(const ushort* __restrict__ A,
                                                   const ushort* __restrict__ Wt,
                                                   ushort* __restrict__ q,
                                                   ushort* __restrict__ k,
                                                   ushort* __restrict__ vt) {
    constexpr int K = 1024;
    extern __shared__ ushort lds[];

    const int L = blockIdx.x;
    const int xcd = L & 7, idx = L >> 3;            // idx 0..63
    const int ci = xcd >> 1, cj = xcd & 1;          // chunk grid 4x2 over 32m x 16n
    const int mo = idx >> 3, no = idx & 7;
    const int m0 = (ci * 8 + mo) * 256;             // 0..8191
    const int n0 = (cj * 8 + no) * 192;             // 0..3071 (spans q|k|v columns)

    const int tid = threadIdx.x;
    const int w = tid >> 6, lane = tid & 63, quad = lane >> 4, l16 = lane & 15;
    const int wm = (w >> 1) * 64, wn = (w & 1) * 96;

    ushort* a0 = lds;                // A [256][64] = 16384 ushorts per buffer
    ushort* a1 = lds + 16384;
    ushort* a2 = lds + 32768;
    ushort* b0 = lds + 49152;        // B [192][64] = 12288 ushorts per buffer
    ushort* b1 = lds + 61440;        // total 73728 ushorts = 144 KiB

    const int lr = lane >> 3;
    const int lc8 = (lane & 7) ^ lr;
    const ushort* Ab = A  + (size_t)(m0 + w * 8 + lr) * K + lc8 * 8;
    const ushort* Bb = Wt + (size_t)(n0 + w * 8 + lr) * K + lc8 * 8;  // Wt = [3072][1024]
    const int dW = w * 512;

#define ISSUE_A(buf_, kk_, a_) async16(Ab + (size_t)(a_) * 64 * K + (kk_), (buf_) + (a_) * 4096 + dW)
#define ISSUE_B(buf_, kk_, c_) async16(Bb + (size_t)(c_) * 64 * K + (kk_), (buf_) + (c_) * 4096 + dW)

    f4v acc[4][6];
    #pragma unroll
    for (int mi = 0; mi < 4; mi++)
        #pragma unroll
        for (int ni = 0; ni < 6; ni++) acc[mi][ni] = 0;

    // ---- prologue: A(0)->a0 (4), B(0)->b0 (3), A(1)->a1 (4); FIFO order matters ----
    #pragma unroll
    for (int a = 0; a < 4; a++) ISSUE_A(a0, 0, a);
    #pragma unroll
    for (int c = 0; c < 3; c++) ISSUE_B(b0, 0, c);
    #pragma unroll
    for (int a = 0; a < 4; a++) ISSUE_A(a1, 64, a);
    asm volatile("s_waitcnt vmcnt(4)" ::: "memory");   // tile 0 landed, A(1) in flight
    asm volatile("s_barrier" ::: "memory");

    for (int t = 0; t < 16; ++t) {
        const int kB = (t + 1) * 64;
        const int kA = (t + 2) * 64;
        s8v af[4][2], bf[2][2];

        // phase 0: read all A + B n0,n1; issue B(t+1)
        RD_A4(a0)
        RD_B2(b0, 0)
        if (t < 15) {
            ISSUE_B(b1, kB, 0);
            ISSUE_B(b1, kB, 1);
            ISSUE_B(b1, kB, 2);
        }
        asm volatile("s_barrier" ::: "memory");
        __builtin_amdgcn_s_setprio(1);
        MFMA16(0)
        __builtin_amdgcn_s_setprio(0);
        asm volatile("s_barrier" ::: "memory");

        // phase 1: read B n2,n3; issue A(t+2) first half
        RD_B2(b0, 2)
        if (t < 14) {
            ISSUE_A(a2, kA, 0);
            ISSUE_A(a2, kA, 1);
        }
        asm volatile("s_barrier" ::: "memory");
        __builtin_amdgcn_s_setprio(1);
        MFMA16(2)
        __builtin_amdgcn_s_setprio(0);
        asm volatile("s_barrier" ::: "memory");

        // phase 2: read B n4,n5; issue A(t+2) second half
        RD_B2(b0, 4)
        if (t < 14) {
            ISSUE_A(a2, kA, 2);
            ISSUE_A(a2, kA, 3);
        }
        asm volatile("s_barrier" ::: "memory");
        __builtin_amdgcn_s_setprio(1);
        MFMA16(4)
        __builtin_amdgcn_s_setprio(0);

        if (t < 14)       asm volatile("s_waitcnt vmcnt(4)" ::: "memory");
        else if (t == 14) asm volatile("s_waitcnt vmcnt(0)" ::: "memory");
        asm volatile("s_barrier" ::: "memory");

        ushort* ta = a0; a0 = a1; a1 = a2; a2 = ta;
        ushort* tb = b0; b0 = b1; b1 = tb;
    }

    // ---- epilogue: per 16-col fragment, z = col>>10 is wave-uniform ----
    #pragma unroll
    for (int mi = 0; mi < 4; mi++)
        #pragma unroll
        for (int ni = 0; ni < 6; ni++) {
            int row = m0 + wm + mi * 16 + quad * 4;
            int col = n0 + wn + ni * 16 + l16;
            int z = col >> 10, cz = col & 1023;
            f4v v = acc[mi][ni];
            if (z < 2) {
                ushort* C = (z == 0) ? q : k;
                #pragma unroll
                for (int rr = 0; rr < 4; rr++)
                    C[(size_t)(row + rr) * 1024 + cz] = f2b(v[rr]);
            } else {
                int b = row >> 11, tok = row & 2047;
                ushort4 pk;
                pk.x = f2b(v[0]); pk.y = f2b(v[1]); pk.z = f2b(v[2]); pk.w = f2b(v[3]);
                *(ushort4*)&vt[(size_t)b * (1024u * 2048u) + (size_t)cz * 2048 + tok] = pk;
            }
        }
#undef ISSUE_A
#undef ISSUE_B
}

// ---------------- E = exp(scale * Q K^T) (bf16, masked), + row sums ----------------
// Same 256x192/144KiB/3-phase pipeline as gemm_qkv (K=1024, NT=16). Triangle tiled
// at BN=192: row-tile mt (256 rows) needs ceil(4(mt+1)/3) n-tiles -> 51/batch,
// 204 blocks total (single ~80%-fill round). Coverage: NT(mt)*192 >= 256(mt+1), so
// every E element gemm_pv reads is written (zeros above diagonal). Fragments with
// colbase >= 2048 are skipped (their K-rows were garbage, masked anyway).
__global__ __launch_bounds__(512, 2) void sgemm_qk(const ushort* __restrict__ Q,
                                                   const ushort* __restrict__ Km,
                                                   ushort* __restrict__ E,
                                                   float* __restrict__ l) {
    constexpr int K = 1024;
    extern __shared__ ushort lds[];

    // bijective XCD swizzle for 204 = 8*25+4: xcd<4 get 26 blocks, xcd>=4 get 25.
    const int L = blockIdx.x;
    const int xcd = L & 7, i = L >> 3;
    const int t = (xcd < 4) ? (xcd * 26 + i) : (104 + (xcd - 4) * 25 + i);
    const int b = t / 51;
    int tt = t - b * 51;
    int mt = 0;
    for (;; mt++) {                      // cnt(mt) = ceil(4(mt+1)/3): 2,3,4,6,7,8,10,11
        int c = (4 * (mt + 1) + 2) / 3;
        if (tt < c) break;
        tt -= c;
    }
    const int nt = tt;
    const int m0 = mt * 256, n0 = nt * 192;
    const ushort* A  = Q  + (size_t)b * 2048 * 1024;
    const ushort* Bt = Km + (size_t)b * 2048 * 1024;
    ushort* Cb = E + (size_t)b * 2048 * 2048;
    float* lb = l + (size_t)b * 2048;

    const int tid = threadIdx.x;
    const int w = tid >> 6, lane = tid & 63, quad = lane >> 4, l16 = lane & 15;
    const int wm = (w >> 1) * 64, wn = (w & 1) * 96;

    ushort* a0 = lds;
    ushort* a1 = lds + 16384;
    ushort* a2 = lds + 32768;
    ushort* b0 = lds + 49152;
    ushort* b1 = lds + 61440;

    const int lr = lane >> 3;
    const int lc8 = (lane & 7) ^ lr;
    const ushort* Ab = A  + (size_t)(m0 + w * 8 + lr) * K + lc8 * 8;
    const ushort* Bb = Bt + (size_t)(n0 + w * 8 + lr) * K + lc8 * 8;
    const int dW = w * 512;

#define ISSUE_A(buf_, kk_, a_) async16(Ab + (size_t)(a_) * 64 * K + (kk_), (buf_) + (a_) * 4096 + dW)
#define ISSUE_B(buf_, kk_, c_) async16(Bb + (size_t)(c_) * 64 * K + (kk_), (buf_) + (c_) * 4096 + dW)

    f4v acc[4][6];
    #pragma unroll
    for (int mi = 0; mi < 4; mi++)
        #pragma unroll
        for (int ni = 0; ni < 6; ni++) acc[mi][ni] = 0;

    #pragma unroll
    for (int a = 0; a < 4; a++) ISSUE_A(a0, 0, a);
    #pragma unroll
    for (int c = 0; c < 3; c++) ISSUE_B(b0, 0, c);
    #pragma unroll
    for (int a = 0; a < 4; a++) ISSUE_A(a1, 64, a);
    asm volatile("s_waitcnt vmcnt(4)" ::: "memory");
    asm volatile("s_barrier" ::: "memory");

    for (int tk = 0; tk < 16; ++tk) {
        const int kB = (tk + 1) * 64;
        const int kA = (tk + 2) * 64;
        s8v af[4][2], bf[2][2];

        RD_A4(a0)
        RD_B2(b0, 0)
        if (tk < 15) {
            ISSUE_B(b1, kB, 0);
            ISSUE_B(b1, kB, 1);
            ISSUE_B(b1, kB, 2);
        }
        asm volatile("s_barrier" ::: "memory");
        __builtin_amdgcn_s_setprio(1);
        MFMA16(0)
        __builtin_amdgcn_s_setprio(0);
        asm volatile("s_barrier" ::: "memory");

        RD_B2(b0, 2)
        if (tk < 14) {
            ISSUE_A(a2, kA, 0);
            ISSUE_A(a2, kA, 1);
        }
        asm volatile("s_barrier" ::: "memory");
        __builtin_amdgcn_s_setprio(1);
        MFMA16(2)
        __builtin_amdgcn_s_setprio(0);
        asm volatile("s_barrier" ::: "memory");

        RD_B2(b0, 4)
        if (tk < 14) {
            ISSUE_A(a2, kA, 2);
            ISSUE_A(a2, kA, 3);
        }
        asm volatile("s_barrier" ::: "memory");
        __builtin_amdgcn_s_setprio(1);
        MFMA16(4)
        __builtin_amdgcn_s_setprio(0);

        if (tk < 14)       asm volatile("s_waitcnt vmcnt(4)" ::: "memory");
        else if (tk == 14) asm volatile("s_waitcnt vmcnt(0)" ::: "memory");
        asm volatile("s_barrier" ::: "memory");

        ushort* ta = a0; a0 = a1; a1 = a2; a2 = ta;
        ushort* tb = b0; b0 = b1; b1 = tb;
    }

    // ---- epilogue: exp + mask + store + per-row partial sums ----
    #pragma unroll
    for (int mi = 0; mi < 4; mi++) {
        float rs[4] = {0.f, 0.f, 0.f, 0.f};
        #pragma unroll
        for (int ni = 0; ni < 6; ni++) {
            const int colbase = n0 + wn + ni * 16;
            if (colbase >= 2048) continue;          // wave-uniform OOB guard
            const int col = colbase + l16;
            f4v v = acc[mi][ni];
            #pragma unroll
            for (int rr = 0; rr < 4; rr++) {
                const int row = m0 + wm + mi * 16 + quad * 4 + rr;
                float e = (col <= row) ? __expf(v[rr] * 0.03125f) : 0.f;
                ushort eb = f2b(e);
                Cb[(size_t)row * 2048 + col] = eb;
                rs[rr] += b2f(eb);
            }
        }
        #pragma unroll
        for (int rr = 0; rr < 4; rr++) {
            float s = rs[rr];
            s += __shfl_xor(s, 1);
            s += __shfl_xor(s, 2);
            s += __shfl_xor(s, 4);
            s += __shfl_xor(s, 8);
            if (l16 == 0)
                atomicAdd(&lb[m0 + wm + mi * 16 + quad * 4 + rr], s);
        }
    }
#undef ISSUE_A
#undef ISSUE_B
}

// ---------------- O = (E @ V) / l : per-batch [2048x1024] fp32 ----------------
// Paired-strip uniform blocks: each block runs TWO 128-row strips sequentially,
// mtA = pair and mtB = 15-pair, so total K-tiles = 2(mtA+1) + 2(mtB+1) = 34 for
// EVERY block -- balance is structural (no dispatch-pairing assumption, R5 lesson).
// Grid 8 pairs x 8 nt x 4 b = 256 blocks = one full round of equal-length blocks.
// Per strip: 128x128 tile, 8 waves 2m x 4n (wave 64x32, acc[4][2]); one phase per
// K-tile {read A(8)+B(4); issue B(t+1)x2 + A(t+2)x2; barrier; 16 MFMA; boundary
// vmcnt(2); barrier}. LDS 80 KiB: A 3-deep + B 2-deep of [128][64]. Plain stores.
__global__ __launch_bounds__(512, 2) void gemm_pv(const ushort* __restrict__ Em,
                                                  const ushort* __restrict__ Vt,
                                                  const float* __restrict__ l,
                                                  float* __restrict__ Out) {
    extern __shared__ ushort lds[];
    const int L = blockIdx.x;                       // 256 blocks, 256%8==0
    const int p = (L & 7) * 32 + (L >> 3);          // XCD-swizzled piece id
    const int pair = p >> 5;                        // 0..7
    const int inner = p & 31;
    const int b = inner >> 3;                       // 0..3
    const int nt = inner & 7;                       // 0..7
    const int n0 = nt * 128;
    const ushort* A  = Em + (size_t)b * 2048 * 2048;
    const ushort* Bt = Vt + (size_t)b * 1024 * 2048;
    const float* lb = l + (size_t)b * 2048;
    float* C = Out + (size_t)b * 2048 * 1024;

    const int tid = threadIdx.x;
    const int w = tid >> 6, lane = tid & 63, quad = lane >> 4, l16 = lane & 15;
    const int wm = (w >> 2) * 64, wn = (w & 3) * 32;

    const int lr = lane >> 3;
    const int lc8 = (lane & 7) ^ lr;
    const int dW = w * 512;

#define ISSUE_A(buf_, kk_, a_) async16(Ab + (size_t)(a_) * 64 * 2048 + (kk_), (buf_) + (a_) * 4096 + dW)
#define ISSUE_B(buf_, kk_, c_) async16(Bb + (size_t)(c_) * 64 * 2048 + (kk_), (buf_) + (c_) * 4096 + dW)

    #pragma unroll
    for (int half = 0; half < 2; ++half) {
        const int mt = half ? (15 - pair) : pair;
        const int m0 = mt * 128;
        const int NT = 2 * (mt + 1);                // K-tiles of 64; K = 128(mt+1)

        ushort* a0 = lds;                // A [128][64] = 8192 ushorts per buffer
        ushort* a1 = lds + 8192;
        ushort* a2 = lds + 16384;
        ushort* b0 = lds + 24576;        // B [128][64] = 8192 ushorts per buffer
        ushort* b1 = lds + 32768;        // total 40960 ushorts = 80 KiB

        const ushort* Ab = A  + (size_t)(m0 + w * 8 + lr) * 2048 + lc8 * 8;
        const ushort* Bb = Bt + (size_t)(n0 + w * 8 + lr) * 2048 + lc8 * 8;

        f4v acc[4][2];
        #pragma unroll
        for (int mi = 0; mi < 4; mi++)
            #pragma unroll
            for (int ni = 0; ni < 2; ni++) acc[mi][ni] = 0;

        // prologue: A(0) (2), B(0) (2), A(1) (2)  [NT >= 2 always]
        #pragma unroll
        for (int a = 0; a < 2; a++) ISSUE_A(a0, 0, a);
        #pragma unroll
        for (int c = 0; c < 2; c++) ISSUE_B(b0, 0, c);
        #pragma unroll
        for (int a = 0; a < 2; a++) ISSUE_A(a1, 64, a);
        asm volatile("s_waitcnt vmcnt(2)" ::: "memory");   // tile 0 landed, A(1) in flight
        asm volatile("s_barrier" ::: "memory");

        for (int tk = 0; tk < NT; ++tk) {
            const int kB = (tk + 1) * 64;
            const int kA = (tk + 2) * 64;
            s8v af[4][2], bf[2][2];

            RD_A4(a0)
            RD_B2(b0, 0)
            if (tk < NT - 1) {
                ISSUE_B(b1, kB, 0);
                ISSUE_B(b1, kB, 1);
            }
            if (tk < NT - 2) {
                ISSUE_A(a2, kA, 0);
                ISSUE_A(a2, kA, 1);
            }
            asm volatile("s_barrier" ::: "memory");
            __builtin_amdgcn_s_setprio(1);
            MFMA16(0)
            __builtin_amdgcn_s_setprio(0);

            // boundary: drain A(t+1)+B(t+1), leave A(t+2) in flight
            if (tk < NT - 2)       asm volatile("s_waitcnt vmcnt(2)" ::: "memory");
            else if (tk == NT - 2) asm volatile("s_waitcnt vmcnt(0)" ::: "memory");
            asm volatile("s_barrier" ::: "memory");

            ushort* ta = a0; a0 = a1; a1 = a2; a2 = ta;
            ushort* tb = b0; b0 = b1; b1 = tb;
        }

        // ---- epilogue: divide by row sums, plain fp32 stores ----
        #pragma unroll
        for (int mi = 0; mi < 4; mi++) {
            const int row = m0 + wm + mi * 16 + quad * 4;
            float inv[4];
            #pragma unroll
            for (int rr = 0; rr < 4; rr++) inv[rr] = 1.f / lb[row + rr];
            #pragma unroll
            for (int ni = 0; ni < 2; ni++) {
                const int col = n0 + wn + ni * 16 + l16;
                f4v v = acc[mi][ni];
                #pragma unroll
                for (int rr = 0; rr < 4; rr++)
                    C[(size_t)(row + rr) * 1024 + col] = v[rr] * inv[rr];
            }
        }
        // all waves are past their a0/b0 reads (final boundary barrier); epilogue
        // touches no LDS, so next half's staging can start immediately.
    }
#undef ISSUE_A
#undef ISSUE_B
}

extern "C" void kernel_launch(void* const* d_in, const int* in_sizes, int n_in,
                              void* d_out, int out_size, void* d_ws, size_t ws_size,
                              hipStream_t stream) {
    const float* x  = (const float*)d_in[0];
    const float* Wq = (const float*)d_in[1];
    const float* Wk = (const float*)d_in[2];
    const float* Wv = (const float*)d_in[3];
    float* out = (float*)d_out;

    static bool init = false;
    if (!init) {
        hipFuncSetAttribute(reinterpret_cast<const void*>(gemm_qkv),
                            hipFuncAttributeMaxDynamicSharedMemorySize, 147456);
        hipFuncSetAttribute(reinterpret_cast<const void*>(sgemm_qk),
                            hipFuncAttributeMaxDynamicSharedMemorySize, 147456);
        hipFuncSetAttribute(reinterpret_cast<const void*>(gemm_pv),
                            hipFuncAttributeMaxDynamicSharedMemorySize, 81920);
        init = true;
    }

    char* ws = (char*)d_ws;
    // workspace layout (MiB offsets), total ~103 MiB:
    //   xb @   0 : 16  bf16 x [8192][1024]
    //   wt @  16 :  6  bf16 W^T x3 [out][in]
    //   q  @  22 : 16  bf16 [8192][1024]
    //   k  @  38 : 16  bf16 [8192][1024]
    //   vt @  54 : 16  bf16 Vt[b][1024][2048]
    //   E  @  70 : 32  bf16 exp(S)[b][2048][2048] (unnormalized, masked)
    //   l  @ 102 : 32 KB fp32 row sums [4][2048]
    const size_t MiB = 1u << 20;
    ushort* xb = (ushort*)(ws);
    ushort* wt = (ushort*)(ws + 16 * MiB);
    ushort* q  = (ushort*)(ws + 22 * MiB);
    ushort* k  = (ushort*)(ws + 38 * MiB);
    ushort* vt = (ushort*)(ws + 54 * MiB);
    ushort* E  = (ushort*)(ws + 70 * MiB);
    float*  l  = (float*)(ws + 102 * MiB);

    prep<<<8192 + 3072, 256, 0, stream>>>(x, xb, l, Wq, Wk, Wv, wt);

    gemm_qkv<<<512, 512, 147456, stream>>>(xb, wt, q, k, vt);
    sgemm_qk<<<204, 512, 147456, stream>>>(q, k, E, l);
    gemm_pv<<<256, 512, 81920, stream>>>(E, vt, l, out);
}

// Round 7
// 209.304 us; speedup vs baseline: 1.0251x; 1.0251x over previous
//
#include <hip/hip_runtime.h>

typedef float  f4v  __attribute__((ext_vector_type(4)));
typedef short  s8v  __attribute__((ext_vector_type(8)));

// fp32 -> bf16 round-to-nearest-even
__device__ __forceinline__ ushort f2b(float f) {
    union { float f; unsigned int u; } v; v.f = f;
    unsigned int u = v.u;
    u += 0x7fffu + ((u >> 16) & 1u);
    return (ushort)(u >> 16);
}
__device__ __forceinline__ float b2f(ushort u) {
    union { unsigned int u; float f; } v; v.u = ((unsigned int)u) << 16;
    return v.f;
}

// async global->LDS, 16B per lane. ldsp MUST be wave-uniform; HW writes
// lane i's 16B at ldsp + i*16 (no per-lane scatter, no padding allowed).
__device__ __forceinline__ void async16(const ushort* g, ushort* ldsp) {
    __builtin_amdgcn_global_load_lds(
        (const __attribute__((address_space(1))) unsigned int*)g,
        (__attribute__((address_space(3))) unsigned int*)ldsp, 16, 0, 0);
}

// -------- fused prep: cast x->bf16, zero l, transpose W x3 (one launch) --------
__global__ __launch_bounds__(256) void prep(const float* __restrict__ in,
                                            ushort* __restrict__ out,
                                            float* __restrict__ l,
                                            const float* __restrict__ w0,
                                            const float* __restrict__ w1,
                                            const float* __restrict__ w2,
                                            ushort* __restrict__ wt) {
    const int L = blockIdx.x, tid = threadIdx.x;
    if (L < 8192) {
        int i = L * 256 + tid;
        if (i < 8192) l[i] = 0.f;   // 4 batches x 2048 rows
        float4 f = ((const float4*)in)[i];
        ushort4 o;
        o.x = f2b(f.x); o.y = f2b(f.y); o.z = f2b(f.z); o.w = f2b(f.w);
        ((ushort4*)out)[i] = o;
        return;
    }
    __shared__ float tile[32][33];
    const int T = L - 8192;
    const int z = T >> 10, rem = T & 1023;
    const int bx = rem & 31, by = rem >> 5;
    const float* W = (z == 0) ? w0 : (z == 1 ? w1 : w2);
    ushort* O = wt + (size_t)z * (1024u * 1024u);
    int x0 = bx * 32, y0 = by * 32;
    int tx = tid & 31, ty = tid >> 5;
    for (int i = 0; i < 4; i++)
        tile[ty + i * 8][tx] = W[(size_t)(y0 + ty + i * 8) * 1024 + x0 + tx];
    __syncthreads();
    for (int i = 0; i < 4; i++)
        O[(size_t)(x0 + ty + i * 8) * 1024 + y0 + tx] = f2b(tile[tx][ty + i * 8]);
}

// ============== shared pipeline macros (counted-vmcnt + fragment read-ahead) ==============
// Both-sides XOR swizzle: global source col pre-swizzled (lc8 = (lane&7)^lr, row%8==lr),
// ds_read col swizzled by ^(l16&7). Linear LDS dest for global_load_lds.
// Read-ahead: fragments for phase p+1 (and next tile's A) are ds_read BEFORE phase p's
// MFMA, so the MFMA's s_waitcnt is a counted lgkmcnt(N) and the LDS drain overlaps the
// matrix pipe (m201 pattern). Raw s_barrier does NOT drain lgkm/vmcnt - that is the point.

#define RD_A4_TO(dst_, buf_)                                                          \
    _Pragma("unroll") for (int mi = 0; mi < 4; mi++)                                  \
    _Pragma("unroll") for (int s = 0; s < 2; s++)                                     \
        dst_[mi][s] = *(const s8v*)&(buf_)[(wm + mi * 16 + l16) * 64 +                \
                                           (((s * 4 + quad) ^ (l16 & 7)) * 8)];

#define RD_B2_TO(dst_, buf_, NI0_)                                                    \
    _Pragma("unroll") for (int j = 0; j < 2; j++)                                     \
    _Pragma("unroll") for (int s = 0; s < 2; s++)                                     \
        dst_[j][s] = *(const s8v*)&(buf_)[(wn + ((NI0_) + j) * 16 + l16) * 64 +       \
                                          (((s * 4 + quad) ^ (l16 & 7)) * 8)];

#define MFMA16F(af_, bf_, NI0_)                                                       \
    _Pragma("unroll") for (int mi = 0; mi < 4; mi++)                                  \
    _Pragma("unroll") for (int j = 0; j < 2; j++)                                     \
    _Pragma("unroll") for (int s = 0; s < 2; s++)                                     \
        acc[mi][(NI0_) + j] = __builtin_amdgcn_mfma_f32_16x16x32_bf16(                \
            af_[mi][s], bf_[j][s], acc[mi][(NI0_) + j], 0, 0, 0);

// 3-phase K-tile body (qkv / qk; NT=16). Entering tile t: AFC_ holds A(t) frags,
// outstanding vmem = A(t+1)x4, a0=A(t) b0=B(t) ordered.
// Mid-tile vmcnt(5) (t<14; 3 at t>=14) retires A(t+1) so next tile's A-frags are
// read from a1 during phase 2, overlapping MFMA. Boundary vmcnt(4) drains B(t+1),
// leaving A(t+2) in flight (never 0 mid-loop).
#define TILE3(t_, AFC_, AFN_)                                                         \
  {                                                                                   \
    const int kB = ((t_) + 1) * 64;                                                   \
    const int kA = ((t_) + 2) * 64;                                                   \
    s8v bf0[2][2], bf1[2][2], bf2[2][2];                                              \
    RD_B2_TO(bf0, b0, 0)                                                              \
    if ((t_) < 15) {                                                                  \
        ISSUE_B(b1, kB, 0);                                                           \
        ISSUE_B(b1, kB, 1);                                                           \
        ISSUE_B(b1, kB, 2);                                                           \
    }                                                                                 \
    RD_B2_TO(bf1, b0, 2)                                                              \
    asm volatile("s_barrier" ::: "memory");                                           \
    __builtin_amdgcn_s_setprio(1);                                                    \
    MFMA16F(AFC_, bf0, 0)                                                             \
    __builtin_amdgcn_s_setprio(0);                                                    \
    asm volatile("s_barrier" ::: "memory");                                           \
    if ((t_) < 14) {                                                                  \
        ISSUE_A(a2, kA, 0);                                                           \
        ISSUE_A(a2, kA, 1);                                                           \
        asm volatile("s_waitcnt vmcnt(5)" ::: "memory");                              \
    } else {                                                                          \
        asm volatile("s_waitcnt vmcnt(3)" ::: "memory");                              \
    }                                                                                 \
    RD_B2_TO(bf2, b0, 4)                                                              \
    asm volatile("s_barrier" ::: "memory");                                           \
    __builtin_amdgcn_s_setprio(1);                                                    \
    MFMA16F(AFC_, bf1, 2)                                                             \
    __builtin_amdgcn_s_setprio(0);                                                    \
    asm volatile("s_barrier" ::: "memory");                                           \
    if ((t_) < 14) {                                                                  \
        ISSUE_A(a2, kA, 2);                                                           \
        ISSUE_A(a2, kA, 3);                                                           \
    }                                                                                 \
    RD_A4_TO(AFN_, a1)                                                                \
    asm volatile("s_barrier" ::: "memory");                                           \
    __builtin_amdgcn_s_setprio(1);                                                    \
    MFMA16F(AFC_, bf2, 4)                                                             \
    __builtin_amdgcn_s_setprio(0);                                                    \
    if ((t_) < 14)       asm volatile("s_waitcnt vmcnt(4)" ::: "memory");             \
    else if ((t_) == 14) asm volatile("s_waitcnt vmcnt(0)" ::: "memory");             \
    asm volatile("s_barrier" ::: "memory");                                           \
    ushort* ta = a0; a0 = a1; a1 = a2; a2 = ta;                                       \
    ushort* tb = b0; b0 = b1; b1 = tb;                                                \
  }

// ---------------- fused QKV projection: 256x192 tile, read-ahead pipeline --------
// Grid 32m x 16n = 512 blocks = exactly 2 full CU-rounds. 8 waves 4m x 2n ->
// wave tile 64x96 (acc[4][6]). LDS 144 KiB: A 3-deep [256][64], B 2-deep [192][64].
__global__ __launch_bounds__(512, 2) void gemm_qkv(const ushort* __restrict__ A,
                                                   const ushort* __restrict__ Wt,
                                                   ushort* __restrict__ q,
                                                   ushort* __restrict__ k,
                                                   ushort* __restrict__ vt) {
    constexpr int K = 1024;
    extern __shared__ ushort lds[];

    const int L = blockIdx.x;
    const int xcd = L & 7, idx = L >> 3;            // idx 0..63
    const int ci = xcd >> 1, cj = xcd & 1;          // chunk grid 4x2 over 32m x 16n
    const int mo = idx >> 3, no = idx & 7;
    const int m0 = (ci * 8 + mo) * 256;             // 0..8191
    const int n0 = (cj * 8 + no) * 192;             // 0..3071 (spans q|k|v columns)

    const int tid = threadIdx.x;
    const int w = tid >> 6, lane = tid & 63, quad = lane >> 4, l16 = lane & 15;
    const int wm = (w >> 1) * 64, wn = (w & 1) * 96;

    ushort* a0 = lds;                // A [256][64] = 16384 ushorts per buffer
    ushort* a1 = lds + 16384;
    ushort* a2 = lds + 32768;
    ushort* b0 = lds + 49152;        // B [192][64] = 12288 ushorts per buffer
    ushort* b1 = lds + 61440;        // total 73728 ushorts = 144 KiB

    const int lr = lane >> 3;
    const int lc8 = (lane & 7) ^ lr;
    const ushort* Ab = A  + (size_t)(m0 + w * 8 + lr) * K + lc8 * 8;
    const ushort* Bb = Wt + (size_t)(n0 + w * 8 + lr) * K + lc8 * 8;  // Wt = [3072][1024]
    const int dW = w * 512;

#define ISSUE_A(buf_, kk_, a_) async16(Ab + (size_t)(a_) * 64 * K + (kk_), (buf_) + (a_) * 4096 + dW)
#define ISSUE_B(buf_, kk_, c_) async16(Bb + (size_t)(c_) * 64 * K + (kk_), (buf_) + (c_) * 4096 + dW)

    f4v acc[4][6];
    #pragma unroll
    for (int mi = 0; mi < 4; mi++)
        #pragma unroll
        for (int ni = 0; ni < 6; ni++) acc[mi][ni] = 0;

    // prologue: A(0)x4, B(0)x3, A(1)x4 (FIFO order matters); vmcnt(4) leaves A(1).
    #pragma unroll
    for (int a = 0; a < 4; a++) ISSUE_A(a0, 0, a);
    #pragma unroll
    for (int c = 0; c < 3; c++) ISSUE_B(b0, 0, c);
    #pragma unroll
    for (int a = 0; a < 4; a++) ISSUE_A(a1, 64, a);
    asm volatile("s_waitcnt vmcnt(4)" ::: "memory");
    asm volatile("s_barrier" ::: "memory");

    s8v afX[4][2], afY[4][2];
    RD_A4_TO(afX, a0)
    for (int tp = 0; tp < 8; ++tp) {       // 16 K-tiles, unrolled x2 for static frags
        TILE3(2 * tp,     afX, afY)
        TILE3(2 * tp + 1, afY, afX)
    }

    // ---- epilogue: per 16-col fragment, z = col>>10 is wave-uniform ----
    #pragma unroll
    for (int mi = 0; mi < 4; mi++)
        #pragma unroll
        for (int ni = 0; ni < 6; ni++) {
            int row = m0 + wm + mi * 16 + quad * 4;
            int col = n0 + wn + ni * 16 + l16;
            int z = col >> 10, cz = col & 1023;
            f4v v = acc[mi][ni];
            if (z < 2) {
                ushort* C = (z == 0) ? q : k;
                #pragma unroll
                for (int rr = 0; rr < 4; rr++)
                    C[(size_t)(row + rr) * 1024 + cz] = f2b(v[rr]);
            } else {
                int b = row >> 11, tok = row & 2047;
                ushort4 pk;
                pk.x = f2b(v[0]); pk.y = f2b(v[1]); pk.z = f2b(v[2]); pk.w = f2b(v[3]);
                *(ushort4*)&vt[(size_t)b * (1024u * 2048u) + (size_t)cz * 2048 + tok] = pk;
            }
        }
#undef ISSUE_A
#undef ISSUE_B
}

// ---------------- E = exp(scale * Q K^T) (bf16, masked), + row sums ----------------
// Same 256x192 read-ahead pipeline (K=1024, NT=16). Triangle tiled at BN=192:
// 51 tiles/batch, 204 blocks (single ~80%-fill round).
__global__ __launch_bounds__(512, 2) void sgemm_qk(const ushort* __restrict__ Q,
                                                   const ushort* __restrict__ Km,
                                                   ushort* __restrict__ E,
                                                   float* __restrict__ l) {
    constexpr int K = 1024;
    extern __shared__ ushort lds[];

    // bijective XCD swizzle for 204 = 8*25+4: xcd<4 get 26 blocks, xcd>=4 get 25.
    const int L = blockIdx.x;
    const int xcd = L & 7, i = L >> 3;
    const int t = (xcd < 4) ? (xcd * 26 + i) : (104 + (xcd - 4) * 25 + i);
    const int b = t / 51;
    int tt = t - b * 51;
    int mt = 0;
    for (;; mt++) {                      // cnt(mt) = ceil(4(mt+1)/3): 2,3,4,6,7,8,10,11
        int c = (4 * (mt + 1) + 2) / 3;
        if (tt < c) break;
        tt -= c;
    }
    const int nt = tt;
    const int m0 = mt * 256, n0 = nt * 192;
    const ushort* A  = Q  + (size_t)b * 2048 * 1024;
    const ushort* Bt = Km + (size_t)b * 2048 * 1024;
    ushort* Cb = E + (size_t)b * 2048 * 2048;
    float* lb = l + (size_t)b * 2048;

    const int tid = threadIdx.x;
    const int w = tid >> 6, lane = tid & 63, quad = lane >> 4, l16 = lane & 15;
    const int wm = (w >> 1) * 64, wn = (w & 1) * 96;

    ushort* a0 = lds;
    ushort* a1 = lds + 16384;
    ushort* a2 = lds + 32768;
    ushort* b0 = lds + 49152;
    ushort* b1 = lds + 61440;

    const int lr = lane >> 3;
    const int lc8 = (lane & 7) ^ lr;
    const ushort* Ab = A  + (size_t)(m0 + w * 8 + lr) * K + lc8 * 8;
    const ushort* Bb = Bt + (size_t)(n0 + w * 8 + lr) * K + lc8 * 8;
    const int dW = w * 512;

#define ISSUE_A(buf_, kk_, a_) async16(Ab + (size_t)(a_) * 64 * K + (kk_), (buf_) + (a_) * 4096 + dW)
#define ISSUE_B(buf_, kk_, c_) async16(Bb + (size_t)(c_) * 64 * K + (kk_), (buf_) + (c_) * 4096 + dW)

    f4v acc[4][6];
    #pragma unroll
    for (int mi = 0; mi < 4; mi++)
        #pragma unroll
        for (int ni = 0; ni < 6; ni++) acc[mi][ni] = 0;

    #pragma unroll
    for (int a = 0; a < 4; a++) ISSUE_A(a0, 0, a);
    #pragma unroll
    for (int c = 0; c < 3; c++) ISSUE_B(b0, 0, c);
    #pragma unroll
    for (int a = 0; a < 4; a++) ISSUE_A(a1, 64, a);
    asm volatile("s_waitcnt vmcnt(4)" ::: "memory");
    asm volatile("s_barrier" ::: "memory");

    s8v afX[4][2], afY[4][2];
    RD_A4_TO(afX, a0)
    for (int tp = 0; tp < 8; ++tp) {
        TILE3(2 * tp,     afX, afY)
        TILE3(2 * tp + 1, afY, afX)
    }

    // ---- epilogue: exp + mask + store + per-row partial sums ----
    #pragma unroll
    for (int mi = 0; mi < 4; mi++) {
        float rs[4] = {0.f, 0.f, 0.f, 0.f};
        #pragma unroll
        for (int ni = 0; ni < 6; ni++) {
            const int colbase = n0 + wn + ni * 16;
            if (colbase >= 2048) continue;          // wave-uniform OOB guard
            const int col = colbase + l16;
            f4v v = acc[mi][ni];
            #pragma unroll
            for (int rr = 0; rr < 4; rr++) {
                const int row = m0 + wm + mi * 16 + quad * 4 + rr;
                float e = (col <= row) ? __expf(v[rr] * 0.03125f) : 0.f;
                ushort eb = f2b(e);
                Cb[(size_t)row * 2048 + col] = eb;
                rs[rr] += b2f(eb);
            }
        }
        #pragma unroll
        for (int rr = 0; rr < 4; rr++) {
            float s = rs[rr];
            s += __shfl_xor(s, 1);
            s += __shfl_xor(s, 2);
            s += __shfl_xor(s, 4);
            s += __shfl_xor(s, 8);
            if (l16 == 0)
                atomicAdd(&lb[m0 + wm + mi * 16 + quad * 4 + rr], s);
        }
    }
#undef ISSUE_A
#undef ISSUE_B
}

// ---------------- O = (E @ V) / l : per-batch [2048x1024] fp32 ----------------
// Paired-strip uniform blocks (34 K-tiles each), read-ahead single-phase body:
// per tile t: issue (t+2) x4, vmcnt(4) retires tile (t+1), barrier, ds_read
// frags(t+1) (12 reads), MFMA(t) -- which needs NO lgkm wait (its frags were read
// last tile), so the full read drain hides under the matrix pipe.
// LDS 96 KiB: A 3-deep + B 3-deep of [128][64]. Plain stores.
__global__ __launch_bounds__(512, 2) void gemm_pv(const ushort* __restrict__ Em,
                                                  const ushort* __restrict__ Vt,
                                                  const float* __restrict__ l,
                                                  float* __restrict__ Out) {
    extern __shared__ ushort lds[];
    const int L = blockIdx.x;                       // 256 blocks, 256%8==0
    const int p = (L & 7) * 32 + (L >> 3);          // XCD-swizzled piece id
    const int pair = p >> 5;                        // 0..7
    const int inner = p & 31;
    const int b = inner >> 3;                       // 0..3
    const int nt = inner & 7;                       // 0..7
    const int n0 = nt * 128;
    const ushort* A  = Em + (size_t)b * 2048 * 2048;
    const ushort* Bt = Vt + (size_t)b * 1024 * 2048;
    const float* lb = l + (size_t)b * 2048;
    float* C = Out + (size_t)b * 2048 * 1024;

    const int tid = threadIdx.x;
    const int w = tid >> 6, lane = tid & 63, quad = lane >> 4, l16 = lane & 15;
    const int wm = (w >> 2) * 64, wn = (w & 3) * 32;

    const int lr = lane >> 3;
    const int lc8 = (lane & 7) ^ lr;
    const int dW = w * 512;

#define ISSUE_A(buf_, kk_, a_) async16(Ab + (size_t)(a_) * 64 * 2048 + (kk_), (buf_) + (a_) * 4096 + dW)
#define ISSUE_B(buf_, kk_, c_) async16(Bb + (size_t)(c_) * 64 * 2048 + (kk_), (buf_) + (c_) * 4096 + dW)

#define TILE1(t_, FCA_, FCB_, FNA_, FNB_)                                             \
  {                                                                                   \
    const int kk = ((t_) + 2) * 64;                                                   \
    if ((t_) < NT - 2) {                                                              \
        ISSUE_A(a2, kk, 0); ISSUE_A(a2, kk, 1);                                       \
        ISSUE_B(b2, kk, 0); ISSUE_B(b2, kk, 1);                                       \
        asm volatile("s_waitcnt vmcnt(4)" ::: "memory");                              \
    } else if ((t_) == NT - 2) {                                                      \
        asm volatile("s_waitcnt vmcnt(0)" ::: "memory");                              \
    }                                                                                 \
    asm volatile("s_barrier" ::: "memory");                                           \
    RD_A4_TO(FNA_, a1)                                                                \
    RD_B2_TO(FNB_, b1, 0)                                                             \
    __builtin_amdgcn_s_setprio(1);                                                    \
    MFMA16F(FCA_, FCB_, 0)                                                            \
    __builtin_amdgcn_s_setprio(0);                                                    \
    ushort* ta = a0; a0 = a1; a1 = a2; a2 = ta;                                       \
    ushort* tb = b0; b0 = b1; b1 = b2; b2 = tb;                                       \
  }

    #pragma unroll
    for (int half = 0; half < 2; ++half) {
        const int mt = half ? (15 - pair) : pair;
        const int m0 = mt * 128;
        const int NT = 2 * (mt + 1);                // K-tiles of 64; even, 2..32

        ushort* a0 = lds;                // A [128][64] = 8192 ushorts per buffer
        ushort* a1 = lds + 8192;
        ushort* a2 = lds + 16384;
        ushort* b0 = lds + 24576;        // B [128][64] = 8192 ushorts per buffer
        ushort* b1 = lds + 32768;
        ushort* b2 = lds + 40960;        // total 49152 ushorts = 96 KiB

        const ushort* Ab = A  + (size_t)(m0 + w * 8 + lr) * 2048 + lc8 * 8;
        const ushort* Bb = Bt + (size_t)(n0 + w * 8 + lr) * 2048 + lc8 * 8;

        f4v acc[4][2];
        #pragma unroll
        for (int mi = 0; mi < 4; mi++)
            #pragma unroll
            for (int ni = 0; ni < 2; ni++) acc[mi][ni] = 0;

        // inter-strip safety: all waves past previous strip's LDS reads before
        // this strip's gload_lds writes can land.
        asm volatile("s_barrier" ::: "memory");

        // prologue: A(0)x2,B(0)x2 then A(1)x2,B(1)x2; vmcnt(4) leaves tile 1.
        ISSUE_A(a0, 0, 0); ISSUE_A(a0, 0, 1);
        ISSUE_B(b0, 0, 0); ISSUE_B(b0, 0, 1);
        ISSUE_A(a1, 64, 0); ISSUE_A(a1, 64, 1);
        ISSUE_B(b1, 64, 0); ISSUE_B(b1, 64, 1);
        asm volatile("s_waitcnt vmcnt(4)" ::: "memory");
        asm volatile("s_barrier" ::: "memory");

        s8v afX[4][2], bfX[2][2], afY[4][2], bfY[2][2];
        RD_A4_TO(afX, a0)
        RD_B2_TO(bfX, b0, 0)
        for (int tk = 0; tk < NT; tk += 2) {        // NT even
            TILE1(tk,     afX, bfX, afY, bfY)
            TILE1(tk + 1, afY, bfY, afX, bfX)
        }

        // ---- epilogue: divide by row sums, plain fp32 stores ----
        #pragma unroll
        for (int mi = 0; mi < 4; mi++) {
            const int row = m0 + wm + mi * 16 + quad * 4;
            float inv[4];
            #pragma unroll
            for (int rr = 0; rr < 4; rr++) inv[rr] = 1.f / lb[row + rr];
            #pragma unroll
            for (int ni = 0; ni < 2; ni++) {
                const int col = n0 + wn + ni * 16 + l16;
                f4v v = acc[mi][ni];
                #pragma unroll
                for (int rr = 0; rr < 4; rr++)
                    C[(size_t)(row + rr) * 1024 + col] = v[rr] * inv[rr];
            }
        }
    }
#undef TILE1
#undef ISSUE_A
#undef ISSUE_B
}

extern "C" void kernel_launch(void* const* d_in, const int* in_sizes, int n_in,
                              void* d_out, int out_size, void* d_ws, size_t ws_size,
                              hipStream_t stream) {
    const float* x  = (const float*)d_in[0];
    const float* Wq = (const float*)d_in[1];
    const float* Wk = (const float*)d_in[2];
    const float* Wv = (const float*)d_in[3];
    float* out = (float*)d_out;

    static bool init = false;
    if (!init) {
        hipFuncSetAttribute(reinterpret_cast<const void*>(gemm_qkv),
                            hipFuncAttributeMaxDynamicSharedMemorySize, 147456);
        hipFuncSetAttribute(reinterpret_cast<const void*>(sgemm_qk),
                            hipFuncAttributeMaxDynamicSharedMemorySize, 147456);
        hipFuncSetAttribute(reinterpret_cast<const void*>(gemm_pv),
                            hipFuncAttributeMaxDynamicSharedMemorySize, 98304);
        init = true;
    }

    char* ws = (char*)d_ws;
    // workspace layout (MiB offsets), total ~103 MiB:
    //   xb @   0 : 16  bf16 x [8192][1024]
    //   wt @  16 :  6  bf16 W^T x3 [out][in]
    //   q  @  22 : 16  bf16 [8192][1024]
    //   k  @  38 : 16  bf16 [8192][1024]
    //   vt @  54 : 16  bf16 Vt[b][1024][2048]
    //   E  @  70 : 32  bf16 exp(S)[b][2048][2048] (unnormalized, masked)
    //   l  @ 102 : 32 KB fp32 row sums [4][2048]
    const size_t MiB = 1u << 20;
    ushort* xb = (ushort*)(ws);
    ushort* wt = (ushort*)(ws + 16 * MiB);
    ushort* q  = (ushort*)(ws + 22 * MiB);
    ushort* k  = (ushort*)(ws + 38 * MiB);
    ushort* vt = (ushort*)(ws + 54 * MiB);
    ushort* E  = (ushort*)(ws + 70 * MiB);
    float*  l  = (float*)(ws + 102 * MiB);

    prep<<<8192 + 3072, 256, 0, stream>>>(x, xb, l, Wq, Wk, Wv, wt);

    gemm_qkv<<<512, 512, 147456, stream>>>(xb, wt, q, k, vt);
    sgemm_qk<<<204, 512, 147456, stream>>>(q, k, E, l);
    gemm_pv<<<256, 512, 98304, stream>>>(E, vt, l, out);
}

// Round 8
// 207.611 us; speedup vs baseline: 1.0335x; 1.0082x over previous
//
#include <hip/hip_runtime.h>

typedef float  f4v  __attribute__((ext_vector_type(4)));
typedef short  s8v  __attribute__((ext_vector_type(8)));

// fp32 -> bf16 round-to-nearest-even
__device__ __forceinline__ ushort f2b(float f) {
    union { float f; unsigned int u; } v; v.f = f;
    unsigned int u = v.u;
    u += 0x7fffu + ((u >> 16) & 1u);
    return (ushort)(u >> 16);
}
__device__ __forceinline__ float b2f(ushort u) {
    union { unsigned int u; float f; } v; v.u = ((unsigned int)u) << 16;
    return v.f;
}

// async global->LDS, 16B per lane. ldsp MUST be wave-uniform; HW writes
// lane i's 16B at ldsp + i*16 (no per-lane scatter, no padding allowed).
__device__ __forceinline__ void async16(const ushort* g, ushort* ldsp) {
    __builtin_amdgcn_global_load_lds(
        (const __attribute__((address_space(1))) unsigned int*)g,
        (__attribute__((address_space(3))) unsigned int*)ldsp, 16, 0, 0);
}

// -------- fused prep: cast x->bf16, zero l, transpose W x3 (one launch) --------
__global__ __launch_bounds__(256) void prep(const float* __restrict__ in,
                                            ushort* __restrict__ out,
                                            float* __restrict__ l,
                                            const float* __restrict__ w0,
                                            const float* __restrict__ w1,
                                            const float* __restrict__ w2,
                                            ushort* __restrict__ wt) {
    const int L = blockIdx.x, tid = threadIdx.x;
    if (L < 8192) {
        int i = L * 256 + tid;
        if (i < 8192) l[i] = 0.f;   // 4 batches x 2048 rows
        float4 f = ((const float4*)in)[i];
        ushort4 o;
        o.x = f2b(f.x); o.y = f2b(f.y); o.z = f2b(f.z); o.w = f2b(f.w);
        ((ushort4*)out)[i] = o;
        return;
    }
    __shared__ float tile[32][33];
    const int T = L - 8192;
    const int z = T >> 10, rem = T & 1023;
    const int bx = rem & 31, by = rem >> 5;
    const float* W = (z == 0) ? w0 : (z == 1 ? w1 : w2);
    ushort* O = wt + (size_t)z * (1024u * 1024u);
    int x0 = bx * 32, y0 = by * 32;
    int tx = tid & 31, ty = tid >> 5;
    for (int i = 0; i < 4; i++)
        tile[ty + i * 8][tx] = W[(size_t)(y0 + ty + i * 8) * 1024 + x0 + tx];
    __syncthreads();
    for (int i = 0; i < 4; i++)
        O[(size_t)(x0 + ty + i * 8) * 1024 + y0 + tx] = f2b(tile[tx][ty + i * 8]);
}

// ===================== shared pipeline macros =====================
// Both-sides XOR swizzle: global source col pre-swizzled (lc8 = (lane&7)^lr, row%8==lr),
// ds_read col swizzled by ^(l16&7). Linear LDS dest for global_load_lds.

// -- in-place read macros (3-phase body; measured-good R5 config) --
#define RD_A4(buf_)                                                                   \
    _Pragma("unroll") for (int mi = 0; mi < 4; mi++)                                  \
    _Pragma("unroll") for (int s = 0; s < 2; s++)                                     \
        af[mi][s] = *(const s8v*)&(buf_)[(wm + mi * 16 + l16) * 64 +                  \
                                         (((s * 4 + quad) ^ (l16 & 7)) * 8)];

#define RD_B2(buf_, NI0_)                                                             \
    _Pragma("unroll") for (int j = 0; j < 2; j++)                                     \
    _Pragma("unroll") for (int s = 0; s < 2; s++)                                     \
        bf[j][s] = *(const s8v*)&(buf_)[(wn + ((NI0_) + j) * 16 + l16) * 64 +         \
                                        (((s * 4 + quad) ^ (l16 & 7)) * 8)];

#define MFMA16(NI0_)                                                                  \
    _Pragma("unroll") for (int mi = 0; mi < 4; mi++)                                  \
    _Pragma("unroll") for (int j = 0; j < 2; j++)                                     \
    _Pragma("unroll") for (int s = 0; s < 2; s++)                                     \
        acc[mi][(NI0_) + j] = __builtin_amdgcn_mfma_f32_16x16x32_bf16(                \
            af[mi][s], bf[j][s], acc[mi][(NI0_) + j], 0, 0, 0);

// -- named-destination read macros (pv read-ahead body; measured-good R7 config) --
#define RD_A4_TO(dst_, buf_)                                                          \
    _Pragma("unroll") for (int mi = 0; mi < 4; mi++)                                  \
    _Pragma("unroll") for (int s = 0; s < 2; s++)                                     \
        dst_[mi][s] = *(const s8v*)&(buf_)[(wm + mi * 16 + l16) * 64 +                \
                                           (((s * 4 + quad) ^ (l16 & 7)) * 8)];

#define RD_B2_TO(dst_, buf_, NI0_)                                                    \
    _Pragma("unroll") for (int j = 0; j < 2; j++)                                     \
    _Pragma("unroll") for (int s = 0; s < 2; s++)                                     \
        dst_[j][s] = *(const s8v*)&(buf_)[(wn + ((NI0_) + j) * 16 + l16) * 64 +       \
                                          (((s * 4 + quad) ^ (l16 & 7)) * 8)];

#define MFMA16F(af_, bf_, NI0_)                                                       \
    _Pragma("unroll") for (int mi = 0; mi < 4; mi++)                                  \
    _Pragma("unroll") for (int j = 0; j < 2; j++)                                     \
    _Pragma("unroll") for (int s = 0; s < 2; s++)                                     \
        acc[mi][(NI0_) + j] = __builtin_amdgcn_mfma_f32_16x16x32_bf16(                \
            af_[mi][s], bf_[j][s], acc[mi][(NI0_) + j], 0, 0, 0);

// ---------------- fused QKV projection: 256x192 tile, counted-vmcnt pipeline --------
// Grid 32m x 16n = 512 blocks = exactly 2 full CU-rounds. 8 waves 4m x 2n ->
// wave tile 64x96 (acc[4][6]). LDS 144 KiB: A 3-deep [256][64], B 2-deep [192][64].
// 3 phases x 16 MFMA per K-tile; boundary vmcnt(4) leaves A(t+2) in flight.
// (R7's fragment read-ahead REGRESSED this body 63->81 us: +16 VGPR and mid-tile
// vmcnt serialization without removing a barrier. Reverted to the R5 measured-good.)
__global__ __launch_bounds__(512, 2) void gemm_qkv(const ushort* __restrict__ A,
                                                   const ushort* __restrict__ Wt,
                                                   ushort* __restrict__ q,
                                                   ushort* __restrict__ k,
                                                   ushort* __restrict__ vt) {
    constexpr int K = 1024;
    extern __shared__ ushort lds[];

    const int L = blockIdx.x;
    const int xcd = L & 7, idx = L >> 3;            // idx 0..63
    const int ci = xcd >> 1, cj = xcd & 1;          // chunk grid 4x2 over 32m x 16n
    const int mo = idx >> 3, no = idx & 7;
    const int m0 = (ci * 8 + mo) * 256;             // 0..8191
    const int n0 = (cj * 8 + no) * 192;             // 0..3071 (spans q|k|v columns)

    const int tid = threadIdx.x;
    const int w = tid >> 6, lane = tid & 63, quad = lane >> 4, l16 = lane & 15;
    const int wm = (w >> 1) * 64, wn = (w & 1) * 96;

    ushort* a0 = lds;                // A [256][64] = 16384 ushorts per buffer
    ushort* a1 = lds + 16384;
    ushort* a2 = lds + 32768;
    ushort* b0 = lds + 49152;        // B [192][64] = 12288 ushorts per buffer
    ushort* b1 = lds + 61440;        // total 73728 ushorts = 144 KiB

    const int lr = lane >> 3;
    const int lc8 = (lane & 7) ^ lr;
    const ushort* Ab = A  + (size_t)(m0 + w * 8 + lr) * K + lc8 * 8;
    const ushort* Bb = Wt + (size_t)(n0 + w * 8 + lr) * K + lc8 * 8;  // Wt = [3072][1024]
    const int dW = w * 512;

#define ISSUE_A(buf_, kk_, a_) async16(Ab + (size_t)(a_) * 64 * K + (kk_), (buf_) + (a_) * 4096 + dW)
#define ISSUE_B(buf_, kk_, c_) async16(Bb + (size_t)(c_) * 64 * K + (kk_), (buf_) + (c_) * 4096 + dW)

    f4v acc[4][6];
    #pragma unroll
    for (int mi = 0; mi < 4; mi++)
        #pragma unroll
        for (int ni = 0; ni < 6; ni++) acc[mi][ni] = 0;

    // ---- prologue: A(0)->a0 (4), B(0)->b0 (3), A(1)->a1 (4); FIFO order matters ----
    #pragma unroll
    for (int a = 0; a < 4; a++) ISSUE_A(a0, 0, a);
    #pragma unroll
    for (int c = 0; c < 3; c++) ISSUE_B(b0, 0, c);
    #pragma unroll
    for (int a = 0; a < 4; a++) ISSUE_A(a1, 64, a);
    asm volatile("s_waitcnt vmcnt(4)" ::: "memory");   // tile 0 landed, A(1) in flight
    asm volatile("s_barrier" ::: "memory");

    for (int t = 0; t < 16; ++t) {
        const int kB = (t + 1) * 64;
        const int kA = (t + 2) * 64;
        s8v af[4][2], bf[2][2];

        // phase 0: read all A + B n0,n1; issue B(t+1)
        RD_A4(a0)
        RD_B2(b0, 0)
        if (t < 15) {
            ISSUE_B(b1, kB, 0);
            ISSUE_B(b1, kB, 1);
            ISSUE_B(b1, kB, 2);
        }
        asm volatile("s_barrier" ::: "memory");
        __builtin_amdgcn_s_setprio(1);
        MFMA16(0)
        __builtin_amdgcn_s_setprio(0);
        asm volatile("s_barrier" ::: "memory");

        // phase 1: read B n2,n3; issue A(t+2) first half
        RD_B2(b0, 2)
        if (t < 14) {
            ISSUE_A(a2, kA, 0);
            ISSUE_A(a2, kA, 1);
        }
        asm volatile("s_barrier" ::: "memory");
        __builtin_amdgcn_s_setprio(1);
        MFMA16(2)
        __builtin_amdgcn_s_setprio(0);
        asm volatile("s_barrier" ::: "memory");

        // phase 2: read B n4,n5; issue A(t+2) second half
        RD_B2(b0, 4)
        if (t < 14) {
            ISSUE_A(a2, kA, 2);
            ISSUE_A(a2, kA, 3);
        }
        asm volatile("s_barrier" ::: "memory");
        __builtin_amdgcn_s_setprio(1);
        MFMA16(4)
        __builtin_amdgcn_s_setprio(0);

        if (t < 14)       asm volatile("s_waitcnt vmcnt(4)" ::: "memory");
        else if (t == 14) asm volatile("s_waitcnt vmcnt(0)" ::: "memory");
        asm volatile("s_barrier" ::: "memory");

        ushort* ta = a0; a0 = a1; a1 = a2; a2 = ta;
        ushort* tb = b0; b0 = b1; b1 = tb;
    }

    // ---- epilogue: per 16-col fragment, z = col>>10 is wave-uniform ----
    #pragma unroll
    for (int mi = 0; mi < 4; mi++)
        #pragma unroll
        for (int ni = 0; ni < 6; ni++) {
            int row = m0 + wm + mi * 16 + quad * 4;
            int col = n0 + wn + ni * 16 + l16;
            int z = col >> 10, cz = col & 1023;
            f4v v = acc[mi][ni];
            if (z < 2) {
                ushort* C = (z == 0) ? q : k;
                #pragma unroll
                for (int rr = 0; rr < 4; rr++)
                    C[(size_t)(row + rr) * 1024 + cz] = f2b(v[rr]);
            } else {
                int b = row >> 11, tok = row & 2047;
                ushort4 pk;
                pk.x = f2b(v[0]); pk.y = f2b(v[1]); pk.z = f2b(v[2]); pk.w = f2b(v[3]);
                *(ushort4*)&vt[(size_t)b * (1024u * 2048u) + (size_t)cz * 2048 + tok] = pk;
            }
        }
#undef ISSUE_A
#undef ISSUE_B
}

// ---------------- E = exp(scale * Q K^T) (bf16, masked), + row sums ----------------
// Same 256x192/144KiB/3-phase pipeline as gemm_qkv (K=1024, NT=16). Triangle tiled
// at BN=192: 51 tiles/batch, 204 blocks (single ~80%-fill round).
__global__ __launch_bounds__(512, 2) void sgemm_qk(const ushort* __restrict__ Q,
                                                   const ushort* __restrict__ Km,
                                                   ushort* __restrict__ E,
                                                   float* __restrict__ l) {
    constexpr int K = 1024;
    extern __shared__ ushort lds[];

    // bijective XCD swizzle for 204 = 8*25+4: xcd<4 get 26 blocks, xcd>=4 get 25.
    const int L = blockIdx.x;
    const int xcd = L & 7, i = L >> 3;
    const int t = (xcd < 4) ? (xcd * 26 + i) : (104 + (xcd - 4) * 25 + i);
    const int b = t / 51;
    int tt = t - b * 51;
    int mt = 0;
    for (;; mt++) {                      // cnt(mt) = ceil(4(mt+1)/3): 2,3,4,6,7,8,10,11
        int c = (4 * (mt + 1) + 2) / 3;
        if (tt < c) break;
        tt -= c;
    }
    const int nt = tt;
    const int m0 = mt * 256, n0 = nt * 192;
    const ushort* A  = Q  + (size_t)b * 2048 * 1024;
    const ushort* Bt = Km + (size_t)b * 2048 * 1024;
    ushort* Cb = E + (size_t)b * 2048 * 2048;
    float* lb = l + (size_t)b * 2048;

    const int tid = threadIdx.x;
    const int w = tid >> 6, lane = tid & 63, quad = lane >> 4, l16 = lane & 15;
    const int wm = (w >> 1) * 64, wn = (w & 1) * 96;

    ushort* a0 = lds;
    ushort* a1 = lds + 16384;
    ushort* a2 = lds + 32768;
    ushort* b0 = lds + 49152;
    ushort* b1 = lds + 61440;

    const int lr = lane >> 3;
    const int lc8 = (lane & 7) ^ lr;
    const ushort* Ab = A  + (size_t)(m0 + w * 8 + lr) * K + lc8 * 8;
    const ushort* Bb = Bt + (size_t)(n0 + w * 8 + lr) * K + lc8 * 8;
    const int dW = w * 512;

#define ISSUE_A(buf_, kk_, a_) async16(Ab + (size_t)(a_) * 64 * K + (kk_), (buf_) + (a_) * 4096 + dW)
#define ISSUE_B(buf_, kk_, c_) async16(Bb + (size_t)(c_) * 64 * K + (kk_), (buf_) + (c_) * 4096 + dW)

    f4v acc[4][6];
    #pragma unroll
    for (int mi = 0; mi < 4; mi++)
        #pragma unroll
        for (int ni = 0; ni < 6; ni++) acc[mi][ni] = 0;

    #pragma unroll
    for (int a = 0; a < 4; a++) ISSUE_A(a0, 0, a);
    #pragma unroll
    for (int c = 0; c < 3; c++) ISSUE_B(b0, 0, c);
    #pragma unroll
    for (int a = 0; a < 4; a++) ISSUE_A(a1, 64, a);
    asm volatile("s_waitcnt vmcnt(4)" ::: "memory");
    asm volatile("s_barrier" ::: "memory");

    for (int tk = 0; tk < 16; ++tk) {
        const int kB = (tk + 1) * 64;
        const int kA = (tk + 2) * 64;
        s8v af[4][2], bf[2][2];

        RD_A4(a0)
        RD_B2(b0, 0)
        if (tk < 15) {
            ISSUE_B(b1, kB, 0);
            ISSUE_B(b1, kB, 1);
            ISSUE_B(b1, kB, 2);
        }
        asm volatile("s_barrier" ::: "memory");
        __builtin_amdgcn_s_setprio(1);
        MFMA16(0)
        __builtin_amdgcn_s_setprio(0);
        asm volatile("s_barrier" ::: "memory");

        RD_B2(b0, 2)
        if (tk < 14) {
            ISSUE_A(a2, kA, 0);
            ISSUE_A(a2, kA, 1);
        }
        asm volatile("s_barrier" ::: "memory");
        __builtin_amdgcn_s_setprio(1);
        MFMA16(2)
        __builtin_amdgcn_s_setprio(0);
        asm volatile("s_barrier" ::: "memory");

        RD_B2(b0, 4)
        if (tk < 14) {
            ISSUE_A(a2, kA, 2);
            ISSUE_A(a2, kA, 3);
        }
        asm volatile("s_barrier" ::: "memory");
        __builtin_amdgcn_s_setprio(1);
        MFMA16(4)
        __builtin_amdgcn_s_setprio(0);

        if (tk < 14)       asm volatile("s_waitcnt vmcnt(4)" ::: "memory");
        else if (tk == 14) asm volatile("s_waitcnt vmcnt(0)" ::: "memory");
        asm volatile("s_barrier" ::: "memory");

        ushort* ta = a0; a0 = a1; a1 = a2; a2 = ta;
        ushort* tb = b0; b0 = b1; b1 = tb;
    }

    // ---- epilogue: exp + mask + store + per-row partial sums ----
    #pragma unroll
    for (int mi = 0; mi < 4; mi++) {
        float rs[4] = {0.f, 0.f, 0.f, 0.f};
        #pragma unroll
        for (int ni = 0; ni < 6; ni++) {
            const int colbase = n0 + wn + ni * 16;
            if (colbase >= 2048) continue;          // wave-uniform OOB guard
            const int col = colbase + l16;
            f4v v = acc[mi][ni];
            #pragma unroll
            for (int rr = 0; rr < 4; rr++) {
                const int row = m0 + wm + mi * 16 + quad * 4 + rr;
                float e = (col <= row) ? __expf(v[rr] * 0.03125f) : 0.f;
                ushort eb = f2b(e);
                Cb[(size_t)row * 2048 + col] = eb;
                rs[rr] += b2f(eb);
            }
        }
        #pragma unroll
        for (int rr = 0; rr < 4; rr++) {
            float s = rs[rr];
            s += __shfl_xor(s, 1);
            s += __shfl_xor(s, 2);
            s += __shfl_xor(s, 4);
            s += __shfl_xor(s, 8);
            if (l16 == 0)
                atomicAdd(&lb[m0 + wm + mi * 16 + quad * 4 + rr], s);
        }
    }
#undef ISSUE_A
#undef ISSUE_B
}

// ---------------- O = (E @ V) / l : per-batch [2048x1024] fp32 ----------------
// Paired-strip uniform blocks (34 K-tiles each), read-ahead single-phase body:
// per tile t: issue (t+2) x4, vmcnt(4) retires tile (t+1), barrier, ds_read
// frags(t+1) (12 reads), MFMA(t) -- which needs NO lgkm wait (its frags were read
// last tile), so the full read drain hides under the matrix pipe. (R7 measured-good:
// this body cut the qk+pv residual by ~23 us; kept verbatim.)
// LDS 96 KiB: A 3-deep + B 3-deep of [128][64]. Plain stores.
__global__ __launch_bounds__(512, 2) void gemm_pv(const ushort* __restrict__ Em,
                                                  const ushort* __restrict__ Vt,
                                                  const float* __restrict__ l,
                                                  float* __restrict__ Out) {
    extern __shared__ ushort lds[];
    const int L = blockIdx.x;                       // 256 blocks, 256%8==0
    const int p = (L & 7) * 32 + (L >> 3);          // XCD-swizzled piece id
    const int pair = p >> 5;                        // 0..7
    const int inner = p & 31;
    const int b = inner >> 3;                       // 0..3
    const int nt = inner & 7;                       // 0..7
    const int n0 = nt * 128;
    const ushort* A  = Em + (size_t)b * 2048 * 2048;
    const ushort* Bt = Vt + (size_t)b * 1024 * 2048;
    const float* lb = l + (size_t)b * 2048;
    float* C = Out + (size_t)b * 2048 * 1024;

    const int tid = threadIdx.x;
    const int w = tid >> 6, lane = tid & 63, quad = lane >> 4, l16 = lane & 15;
    const int wm = (w >> 2) * 64, wn = (w & 3) * 32;

    const int lr = lane >> 3;
    const int lc8 = (lane & 7) ^ lr;
    const int dW = w * 512;

#define ISSUE_A(buf_, kk_, a_) async16(Ab + (size_t)(a_) * 64 * 2048 + (kk_), (buf_) + (a_) * 4096 + dW)
#define ISSUE_B(buf_, kk_, c_) async16(Bb + (size_t)(c_) * 64 * 2048 + (kk_), (buf_) + (c_) * 4096 + dW)

#define TILE1(t_, FCA_, FCB_, FNA_, FNB_)                                             \
  {                                                                                   \
    const int kk = ((t_) + 2) * 64;                                                   \
    if ((t_) < NT - 2) {                                                              \
        ISSUE_A(a2, kk, 0); ISSUE_A(a2, kk, 1);                                       \
        ISSUE_B(b2, kk, 0); ISSUE_B(b2, kk, 1);                                       \
        asm volatile("s_waitcnt vmcnt(4)" ::: "memory");                              \
    } else if ((t_) == NT - 2) {                                                      \
        asm volatile("s_waitcnt vmcnt(0)" ::: "memory");                              \
    }                                                                                 \
    asm volatile("s_barrier" ::: "memory");                                           \
    RD_A4_TO(FNA_, a1)                                                                \
    RD_B2_TO(FNB_, b1, 0)                                                             \
    __builtin_amdgcn_s_setprio(1);                                                    \
    MFMA16F(FCA_, FCB_, 0)                                                            \
    __builtin_amdgcn_s_setprio(0);                                                    \
    ushort* ta = a0; a0 = a1; a1 = a2; a2 = ta;                                       \
    ushort* tb = b0; b0 = b1; b1 = b2; b2 = tb;                                       \
  }

    #pragma unroll
    for (int half = 0; half < 2; ++half) {
        const int mt = half ? (15 - pair) : pair;
        const int m0 = mt * 128;
        const int NT = 2 * (mt + 1);                // K-tiles of 64; even, 2..32

        ushort* a0 = lds;                // A [128][64] = 8192 ushorts per buffer
        ushort* a1 = lds + 8192;
        ushort* a2 = lds + 16384;
        ushort* b0 = lds + 24576;        // B [128][64] = 8192 ushorts per buffer
        ushort* b1 = lds + 32768;
        ushort* b2 = lds + 40960;        // total 49152 ushorts = 96 KiB

        const ushort* Ab = A  + (size_t)(m0 + w * 8 + lr) * 2048 + lc8 * 8;
        const ushort* Bb = Bt + (size_t)(n0 + w * 8 + lr) * 2048 + lc8 * 8;

        f4v acc[4][2];
        #pragma unroll
        for (int mi = 0; mi < 4; mi++)
            #pragma unroll
            for (int ni = 0; ni < 2; ni++) acc[mi][ni] = 0;

        // inter-strip safety: all waves past previous strip's LDS reads before
        // this strip's gload_lds writes can land.
        asm volatile("s_barrier" ::: "memory");

        // prologue: A(0)x2,B(0)x2 then A(1)x2,B(1)x2; vmcnt(4) leaves tile 1.
        ISSUE_A(a0, 0, 0); ISSUE_A(a0, 0, 1);
        ISSUE_B(b0, 0, 0); ISSUE_B(b0, 0, 1);
        ISSUE_A(a1, 64, 0); ISSUE_A(a1, 64, 1);
        ISSUE_B(b1, 64, 0); ISSUE_B(b1, 64, 1);
        asm volatile("s_waitcnt vmcnt(4)" ::: "memory");
        asm volatile("s_barrier" ::: "memory");

        s8v afX[4][2], bfX[2][2], afY[4][2], bfY[2][2];
        RD_A4_TO(afX, a0)
        RD_B2_TO(bfX, b0, 0)
        for (int tk = 0; tk < NT; tk += 2) {        // NT even
            TILE1(tk,     afX, bfX, afY, bfY)
            TILE1(tk + 1, afY, bfY, afX, bfX)
        }

        // ---- epilogue: divide by row sums, plain fp32 stores ----
        #pragma unroll
        for (int mi = 0; mi < 4; mi++) {
            const int row = m0 + wm + mi * 16 + quad * 4;
            float inv[4];
            #pragma unroll
            for (int rr = 0; rr < 4; rr++) inv[rr] = 1.f / lb[row + rr];
            #pragma unroll
            for (int ni = 0; ni < 2; ni++) {
                const int col = n0 + wn + ni * 16 + l16;
                f4v v = acc[mi][ni];
                #pragma unroll
                for (int rr = 0; rr < 4; rr++)
                    C[(size_t)(row + rr) * 1024 + col] = v[rr] * inv[rr];
            }
        }
    }
#undef TILE1
#undef ISSUE_A
#undef ISSUE_B
}

extern "C" void kernel_launch(void* const* d_in, const int* in_sizes, int n_in,
                              void* d_out, int out_size, void* d_ws, size_t ws_size,
                              hipStream_t stream) {
    const float* x  = (const float*)d_in[0];
    const float* Wq = (const float*)d_in[1];
    const float* Wk = (const float*)d_in[2];
    const float* Wv = (const float*)d_in[3];
    float* out = (float*)d_out;

    static bool init = false;
    if (!init) {
        hipFuncSetAttribute(reinterpret_cast<const void*>(gemm_qkv),
                            hipFuncAttributeMaxDynamicSharedMemorySize, 147456);
        hipFuncSetAttribute(reinterpret_cast<const void*>(sgemm_qk),
                            hipFuncAttributeMaxDynamicSharedMemorySize, 147456);
        hipFuncSetAttribute(reinterpret_cast<const void*>(gemm_pv),
                            hipFuncAttributeMaxDynamicSharedMemorySize, 98304);
        init = true;
    }

    char* ws = (char*)d_ws;
    // workspace layout (MiB offsets), total ~103 MiB:
    //   xb @   0 : 16  bf16 x [8192][1024]
    //   wt @  16 :  6  bf16 W^T x3 [out][in]
    //   q  @  22 : 16  bf16 [8192][1024]
    //   k  @  38 : 16  bf16 [8192][1024]
    //   vt @  54 : 16  bf16 Vt[b][1024][2048]
    //   E  @  70 : 32  bf16 exp(S)[b][2048][2048] (unnormalized, masked)
    //   l  @ 102 : 32 KB fp32 row sums [4][2048]
    const size_t MiB = 1u << 20;
    ushort* xb = (ushort*)(ws);
    ushort* wt = (ushort*)(ws + 16 * MiB);
    ushort* q  = (ushort*)(ws + 22 * MiB);
    ushort* k  = (ushort*)(ws + 38 * MiB);
    ushort* vt = (ushort*)(ws + 54 * MiB);
    ushort* E  = (ushort*)(ws + 70 * MiB);
    float*  l  = (float*)(ws + 102 * MiB);

    prep<<<8192 + 3072, 256, 0, stream>>>(x, xb, l, Wq, Wk, Wv, wt);

    gemm_qkv<<<512, 512, 147456, stream>>>(xb, wt, q, k, vt);
    sgemm_qk<<<204, 512, 147456, stream>>>(q, k, E, l);
    gemm_pv<<<256, 512, 98304, stream>>>(E, vt, l, out);
}